// Round 13
// baseline (164.591 us; speedup 1.0000x reference)
//
#include <hip/hip_runtime.h>

// MLP: 64 × (Linear(5,5)+ReLU) then Linear(5,1), BATCH = 1048576 rows.
// R13: asm-guaranteed v_pk_fma_f32 (all plain "v" operands — R5 proved 30
// such islands compile clean; its bloat was the "s"-constraint
// readfirstlane) + running layer pointer so ALL weight loads are immediate
// offsets (0..232) from one uniform base (SALU bump, no per-load 64-bit
// VALU address math — the suspected +50 slots/layer in R4).
//  - weights pre-duplicated to (w,w) f2 pairs (prep kernel, d_ws):
//    layer l at pair l*30: 25 W pairs (j-major) then 5 bias pairs.
//  - per layer: 12 dwordx4 (pairs 0..23) + 1 dwordx2 (pair 24) +
//    5 dwordx2 bias loads BORN AS the accumulators (zero init VALU);
//    25 pk_fma + 5 pk_max = 30 VALU. f2 halves of f4 = free subregs.
//  - 2 rows/thread -> 2048 blocks = 8 blocks/CU (occupancy cap).

#define MLP_DEPTH 64
#define MLP_D 5
#define ROWS 2

typedef float f2 __attribute__((ext_vector_type(2)));
typedef float f4 __attribute__((ext_vector_type(4)));

// acc += h * w   (all VGPR pairs; guaranteed packed)
#define PK_FMA(acc, hv, wv) \
    asm("v_pk_fma_f32 %0, %1, %2, %0" : "+v"(acc) : "v"(hv), "v"(wv))

// d_ws: pair idx p: layers: l*30 + k, k<25 -> W[l][k/5][k%5] (j-major),
// k>=25 -> b[l][k-25]. Then 6 pairs: W_out[0..4], b_out. (w,w) duplicated.
__global__ __launch_bounds__(256) void MLP_prep_kernel(
    const float* __restrict__ Ws, const float* __restrict__ bs,
    const float* __restrict__ W_out, const float* __restrict__ b_out,
    float* __restrict__ ws)
{
    const int idx = blockIdx.x * blockDim.x + threadIdx.x;
    const int npairs_layers = MLP_DEPTH * 30;
    if (idx < npairs_layers) {
        const int l = idx / 30, k = idx % 30;
        const float v = (k < 25) ? Ws[l * 25 + k] : bs[l * MLP_D + (k - 25)];
        ws[2 * idx + 0] = v;
        ws[2 * idx + 1] = v;
    } else if (idx < npairs_layers + 6) {
        const int k = idx - npairs_layers;
        const float v = (k < MLP_D) ? W_out[k] : b_out[0];
        ws[2 * idx + 0] = v;
        ws[2 * idx + 1] = v;
    }
}

__global__ __launch_bounds__(256) void MLP_89687507075104_kernel(
    const float* __restrict__ x,    // [n, 5]
    const f2* __restrict__ wdup,    // duplicated pairs, layout above
    float* __restrict__ out,        // [n]
    int n)
{
    const int t = blockIdx.x * blockDim.x + threadIdx.x;
    const long row0 = (long)t * ROWS;
    if (row0 >= n) return;

    // rows row0,row0+1 = 10 contiguous floats (8B-aligned f2 loads).
    const f2* xp = reinterpret_cast<const f2*>(x + row0 * MLP_D);
    const f2 v0 = xp[0], v1 = xp[1], v2 = xp[2], v3 = xp[3], v4 = xp[4];
    f2 h[MLP_D];
    h[0] = (f2){ v0.x, v2.y };
    h[1] = (f2){ v0.y, v3.x };
    h[2] = (f2){ v1.x, v3.y };
    h[3] = (f2){ v1.y, v4.x };
    h[4] = (f2){ v2.x, v4.y };

    const f2* p = wdup;  // running layer base (uniform; bumped by +30/layer)

#pragma unroll
    for (int l = 0; l < MLP_DEPTH; ++l) {
        const f4* p4 = reinterpret_cast<const f4*>(p);
        // Weight pairs 0..23 as 12 dwordx4 (imm offsets 0..176).
        f4 m[12];
#pragma unroll
        for (int q = 0; q < 12; ++q) m[q] = p4[q];
        // Pair 24 (W[4][4]) as dwordx2 (imm offset 192).
        const f2 w24 = p[24];
        // Bias pairs 25..29 load DIRECTLY as accumulators (offsets 200..232).
        f2 a[MLP_D];
#pragma unroll
        for (int j = 0; j < MLP_D; ++j) a[j] = p[25 + j];

#pragma unroll
        for (int j = 0; j < MLP_D; ++j) {
#pragma unroll
            for (int i = 0; i < MLP_D; ++i) {
                const int k = j * MLP_D + i;
                if (k == 24) {
                    PK_FMA(a[j], h[i], w24);
                } else if (k & 1) {
                    const f2 w = __builtin_shufflevector(m[k >> 1], m[k >> 1], 2, 3);
                    PK_FMA(a[j], h[i], w);
                } else {
                    const f2 w = __builtin_shufflevector(m[k >> 1], m[k >> 1], 0, 1);
                    PK_FMA(a[j], h[i], w);
                }
            }
        }
#pragma unroll
        for (int j = 0; j < MLP_D; ++j)
            h[j] = __builtin_elementwise_max(a[j], (f2)0.0f);  // v_pk_max_f32

        p += 30;
    }

    // Output layer: pairs p[0..4] = W_out, p[5] = b_out (p = wdup + 64*30).
    f2 o = p[5];                       // acc born from b_out pair load
#pragma unroll
    for (int i = 0; i < MLP_D; ++i) {
        const f2 w = p[i];
        PK_FMA(o, h[i], w);
    }
    *reinterpret_cast<f2*>(out + row0) = o;
}

extern "C" void kernel_launch(void* const* d_in, const int* in_sizes, int n_in,
                              void* d_out, int out_size, void* d_ws, size_t ws_size,
                              hipStream_t stream) {
    const float* x     = (const float*)d_in[0];
    const float* Ws    = (const float*)d_in[1];
    const float* bs    = (const float*)d_in[2];
    const float* W_out = (const float*)d_in[3];
    const float* b_out = (const float*)d_in[4];
    float* out = (float*)d_out;
    float* ws  = (float*)d_ws;   // needs (64*30+6)*2*4 = 15,408 B

    const int n = in_sizes[0] / MLP_D;  // batch rows (1048576)

    const int npairs = MLP_DEPTH * 30 + 6;
    MLP_prep_kernel<<<(npairs + 255) / 256, 256, 0, stream>>>(Ws, bs, W_out, b_out, ws);

    const int block = 256;
    const int threads_needed = (n + ROWS - 1) / ROWS;
    const int grid = (threads_needed + block - 1) / block;  // 2048
    MLP_89687507075104_kernel<<<grid, block, 0, stream>>>(
        x, reinterpret_cast<const f2*>(ws), out, n);
}